// Round 1
// 136.453 us; speedup vs baseline: 1.0961x; 1.0961x over previous
//
#include <hip/hip_runtime.h>

// CTC loss forward, f64 prob-domain with power-of-2 rescaling.
// v2: 4-wave GHOST-ZONE decomposition of the S=513 state axis.
// Each of 4 waves computes a 256-state region = 128-129 OWNED states plus a
// 64-state halo PAD below. CTC flow is strictly forward and moves <=2
// states/step, so missing-inflow contamination from the region bottom
// (DPP bound_ctrl feeds 0) reaches at most 2*32=64 states per 32-step chunk
// -- exactly the pad. Waves exchange owned values through LDS once per
// chunk, at the (now wave-split) y_pred staging boundary. Pad values are
// strict underestimates (missing inflow only removes non-negative mass), so
// they never overflow and never pollute owned states. Owned alphas are
// computed with identical f64 ops in identical order as the single-wave
// version, and the rescale anchor is the same global masked max (4-way LDS
// max of per-wave DPP maxes) -> bitwise-identical output.
// Per lane: 4 states (vs 9), 10 f64 ops/step (vs 22), 3 p-expansions (vs 5),
// 6 LDS gathers/pair (vs 10). Sync cost: 2 barriers + ~6 LDS ops per chunk.

#define Bc 64
#define Tc 1024
#define Cc 128
#define Lc 256
#define Sc 513
#define BLANKc 127
#define CHUNK 32
#define NCHUNK (Tc / CHUNK)
#define NW 4
#define PADS 64

constexpr float EPSF = 1e-7f;

#define DPPMAXI(x, ctrl) max(x, __builtin_amdgcn_update_dpp( \
    0, x, ctrl, 0xf, 0xf, true))

__device__ __forceinline__ double dpp_wave_shr1_f64(double x) {
    // lane l <- lane l-1; lane 0 <- 0 (bound_ctrl)
    union { double d; int i[2]; } u, r;
    u.d = x;
    r.i[0] = __builtin_amdgcn_update_dpp(0, u.i[0], 0x138, 0xf, 0xf, true);
    r.i[1] = __builtin_amdgcn_update_dpp(0, u.i[1], 0x138, 0xf, 0xf, true);
    return r.d;
}

__global__ __launch_bounds__(256) void ctc_kernel(
    const int* __restrict__ y_true,        // [B, L]
    const float* __restrict__ y_pred,      // [B, T, C]
    const int* __restrict__ input_length,  // [B, 1]
    const int* __restrict__ label_length,  // [B, 1]
    float* __restrict__ out)               // [B, 1]
{
    const int b = blockIdx.x;
    const int tid = (int)threadIdx.x;
    const int wid = tid >> 6;              // wave 0..3
    const int lane = tid & 63;

    __shared__ float bufs[3][CHUNK * Cc];  // 3 x 16 KB staged y_pred rows
    __shared__ double alpha_sh[Sc];        // owned-alpha exchange + epilogue
    __shared__ int emax_sh[NW];            // per-wave masked exponent max

    const int lab_len = label_length[b];
    const int in_len  = min(input_length[b], Tc);
    const float* yp = y_pred + (size_t)b * Tc * Cc;
    const int* lab = y_true + b * Lc;

    // ---- region geometry (all starts EVEN so state parity per j is uniform)
    // regions: w0 [0,256) w1 [64,320) w2 [192,448) w3 [320,576)
    // owned:   w0 [0,128) w1 [128,256) w2 [256,384) w3 [384,513)
    const int start = (wid == 0) ? 0 : (128 * wid - PADS);
    const int own_s = 128 * wid;
    const int own_e = (wid == NW - 1) ? Sc : 128 * (wid + 1);
    const int s0 = start + 4 * lane;       // even; lane holds states s0..s0+3

    // ---- per-lane static metadata (states ext: even=blank, odd=label) ----
    const int li0 = s0 >> 1;               // label idx of state s0+1
    const int li0c = min(li0, Lc - 1);     // clamp: junk states read junk (benign)
    const int li1c = min(li0 + 1, Lc - 1); // label idx of state s0+3
    const int ca = lab[li0c];
    const int cb = lab[li1c];
    const double sm_a = (li0 > 0 && ca != BLANKc && ca != lab[li0c - 1]) ? 1.0 : 0.0;
    const double sm_b = (cb != BLANKc && cb != ca) ? 1.0 : 0.0;

    const int S2 = 2 * lab_len + 1;
    const bool ow0 = (s0     >= own_s) && (s0     < own_e);
    const bool ow1 = (s0 + 1 >= own_s) && (s0 + 1 < own_e);
    const bool ow2 = (s0 + 2 >= own_s) && (s0 + 2 < own_e);
    const bool ow3 = (s0 + 3 >= own_s) && (s0 + 3 < own_e);
    const int om0 = (ow0 && s0     < S2) ? -1 : 0;   // anchor mask: owned & valid
    const int om1 = (ow1 && s0 + 1 < S2) ? -1 : 0;
    const int om2 = (ow2 && s0 + 2 < S2) ? -1 : 0;
    const int om3 = (ow3 && s0 + 3 < S2) ? -1 : 0;

    // ---- staging: each wave DMAs its quarter of a 16 KB chunk ----
    auto stage = [&](int k2, float* dstbuf) {
        const float* g = yp + (size_t)k2 * (CHUNK * Cc) + lane * 4;
        #pragma unroll
        for (int q = 0; q < 4; ++q) {
            const int i = wid * 4 + q;
            __builtin_amdgcn_global_load_lds(
                (const __attribute__((address_space(1))) void*)(g + i * 256),
                (__attribute__((address_space(3))) void*)(dstbuf + i * 256),
                16, 0, 0);
        }
    };

    // ---- alpha registers (f64): 4 states per lane ----
    double a0 = 0, a1 = 0, a2 = 0, a3 = 0;
    double n3 = 0;                         // pipelined dpp(a3) = left-neighbor top
    int tote = 0;

    // two p-sets, expanded one step ahead of use
    double Eb, Ea, Ec;                     // even-row: blank, label ca, label cb
    double Ob, Oa, Oc;                     // odd-row

    // pair slots: even idx = row 2q, odd idx = row 2q+1; slot[q&1] holds pair q
    float s01[6], s23[6];

    auto gpair = [&](const float* rowp, float* sl) {
        sl[0] = rowp[BLANKc]; sl[1] = rowp[BLANKc + Cc];
        sl[2] = rowp[ca];     sl[3] = rowp[ca + Cc];
        sl[4] = rowp[cb];     sl[5] = rowp[cb + Cc];
    };
    auto expandE = [&](const float* sl) {
        Eb = (double)(sl[0] + EPSF); Ea = (double)(sl[2] + EPSF);
        Ec = (double)(sl[4] + EPSF);
    };
    auto expandO = [&](const float* sl) {
        Ob = (double)(sl[1] + EPSF); Oa = (double)(sl[3] + EPSF);
        Oc = (double)(sl[5] + EPSF);
    };
    auto stepE = [&]() {
        const double t3 = __fma_rn(sm_b, a1, a3 + a2);
        const double t2 = a2 + a1;
        const double t1 = __fma_rn(sm_a, n3, a1 + a0);
        const double t0 = a0 + n3;
        a3 = t3 * Ec;
        n3 = dpp_wave_shr1_f64(a3);
        a2 = t2 * Eb; a1 = t1 * Ea; a0 = t0 * Eb;
    };
    auto stepO = [&]() {
        const double t3 = __fma_rn(sm_b, a1, a3 + a2);
        const double t2 = a2 + a1;
        const double t1 = __fma_rn(sm_a, n3, a1 + a0);
        const double t0 = a0 + n3;
        a3 = t3 * Oc;
        n3 = dpp_wave_shr1_f64(a3);
        a2 = t2 * Ob; a1 = t1 * Oa; a0 = t0 * Ob;
    };

    // ---- per-chunk sync: exchange owned alphas, global rescale, pad refresh,
    //      stage chunk stage_k. 2 barriers; alpha_sh/emax_sh reuse is safe
    //      because next writes happen only after barrier #2.
    auto syncex = [&](int stage_k) {
        int e =        om0 & (__double2hiint(a0) >> 20);
        e = max(e, om1 & (__double2hiint(a1) >> 20));
        e = max(e, om2 & (__double2hiint(a2) >> 20));
        e = max(e, om3 & (__double2hiint(a3) >> 20));
        e = DPPMAXI(e, 0x111);   // row_shr:1
        e = DPPMAXI(e, 0x112);   // row_shr:2
        e = DPPMAXI(e, 0x114);   // row_shr:4
        e = DPPMAXI(e, 0x118);   // row_shr:8
        e = DPPMAXI(e, 0x142);   // row_bcast:15
        e = DPPMAXI(e, 0x143);   // row_bcast:31
        if (lane == 63) emax_sh[wid] = e;
        if (ow0) alpha_sh[s0]     = a0;
        if (ow1) alpha_sh[s0 + 1] = a1;
        if (ow2) alpha_sh[s0 + 2] = a2;
        if (ow3) alpha_sh[s0 + 3] = a3;
        __builtin_amdgcn_s_waitcnt(0x0F70);  // vmcnt(0): my stage DMA landed
        __syncthreads();                     // all chunk reads done, LDS visible
        if (stage_k < NCHUNK) stage(stage_k, bufs[stage_k % 3]);
        const int eg = max(max(emax_sh[0], emax_sh[1]),
                           max(emax_sh[2], emax_sh[3]));
        const int sexp = min(max(2046 - eg, 1), 2045);
        const double sc = __hiloint2double(sexp << 20, 0);  // exact power of 2
        tote += 1023 - sexp;
        if (wid > 0 && lane < (PADS / 4)) {  // refresh halo pad from owner below
            a0 = alpha_sh[s0];     a1 = alpha_sh[s0 + 1];
            a2 = alpha_sh[s0 + 2]; a3 = alpha_sh[s0 + 3];
        }
        a0 *= sc; a1 *= sc; a2 *= sc; a3 *= sc;
        n3 = dpp_wave_shr1_f64(a3);          // rebuild neighbor pipe post-refresh
        __syncthreads();                     // protect alpha_sh/emax_sh reuse
    };

    // ---- prologue ----
    stage(0, bufs[0]);
    stage(1, bufs[1]);
    stage(2, bufs[2]);
    __builtin_amdgcn_s_waitcnt(0x0F70);      // my quarter landed
    __syncthreads();                         // everyone's quarter landed

    if (wid == 0 && lane == 0) {
        a0 = (double)(bufs[0][BLANKc] + EPSF);               // s=0
        if (lab_len > 0) a1 = (double)(bufs[0][ca] + EPSF);  // s=1 (ca=lab[0])
    }

    // prime slots & p pipeline:
    // pair q=1 (rows 2,3) -> slot1; pair q=2 (rows 4,5) -> slot0
    gpair(bufs[0] + 2 * Cc, s23);
    gpair(bufs[0] + 4 * Cc, s01);
    {   // row 1 direct -> odd set; row 2 -> even set
        const float* r1 = bufs[0] + 1 * Cc;
        Ob = (double)(r1[BLANKc] + EPSF);
        Oa = (double)(r1[ca] + EPSF);
        Oc = (double)(r1[cb] + EPSF);
    }
    expandE(s23);                        // row 2

    // ---- step t=1 (lone odd step) ----
    if (1 < in_len) stepO();
    expandO(s23);                        // row 3 for t=3

    // ---- chunk 0: pairs q=1..15 (rows 2..31) ----
    {
        const float* rb  = bufs[0];
        const float* rbn = bufs[1];
        #pragma unroll
        for (int qi = 1; qi < 16; ++qi) {
            const int rr = 2 * qi;
            if (rr < in_len) stepE();
            expandE((qi & 1) ? s01 : s23);     // row rr+2 from slot[(qi+1)&1]
            if (rr + 1 < in_len) stepO();
            expandO((qi & 1) ? s01 : s23);     // row rr+3
            const float* nxt = (rr + 4 < CHUNK) ? (rb + (rr + 4) * Cc)
                                                : (rbn + (rr + 4 - CHUNK) * Cc);
            gpair(nxt, (qi & 1) ? s23 : s01);  // pair qi+2 -> slot[qi&1]
        }
    }
    syncex(3);

    // ---- chunks 1..31: unified pair pipeline ----
    for (int k = 1; k < NCHUNK; ++k) {
        const float* rb  = bufs[k % 3];
        const float* rbn = bufs[(k + 1) % 3];   // k=31: dead reads, safe
        const int tbase = k * CHUNK;
        if (tbase + CHUNK <= in_len) {
            #pragma unroll
            for (int qi = 0; qi < 16; ++qi) {
                const int rr = 2 * qi;
                stepE();
                expandE((qi & 1) ? s01 : s23);
                stepO();
                expandO((qi & 1) ? s01 : s23);
                const float* nxt = (rr + 4 < CHUNK) ? (rb + (rr + 4) * Cc)
                                                    : (rbn + (rr + 4 - CHUNK) * Cc);
                gpair(nxt, (qi & 1) ? s23 : s01);
            }
        } else {
            #pragma unroll 2
            for (int qi = 0; qi < 16; ++qi) {
                const int rr = 2 * qi;
                if (tbase + rr < in_len) stepE();
                expandE((qi & 1) ? s01 : s23);
                if (tbase + rr + 1 < in_len) stepO();
                expandO((qi & 1) ? s01 : s23);
                const float* nxt = (rr + 4 < CHUNK) ? (rb + (rr + 4) * Cc)
                                                    : (rbn + (rr + 4 - CHUNK) * Cc);
                gpair(nxt, (qi & 1) ? s23 : s01);
            }
        }
        if (k < NCHUNK - 1) syncex(k + 3);
    }

    // ---- epilogue: owners publish final (pre-scale) alphas + current tote ----
    if (ow0) alpha_sh[s0]     = a0;
    if (ow1) alpha_sh[s0 + 1] = a1;
    if (ow2) alpha_sh[s0 + 2] = a2;
    if (ow3) alpha_sh[s0 + 3] = a3;
    __syncthreads();
    if (tid == 0) {
        const double eb = alpha_sh[2 * lab_len];
        const double el = (lab_len > 0) ? alpha_sh[2 * lab_len - 1] : 0.0;
        const double loss = -(log(eb + el) + (double)tote * 0.6931471805599453);
        out[b] = (float)loss;
    }
}

extern "C" void kernel_launch(void* const* d_in, const int* in_sizes, int n_in,
                              void* d_out, int out_size, void* d_ws, size_t ws_size,
                              hipStream_t stream) {
    const int*   y_true       = (const int*)d_in[0];
    const float* y_pred       = (const float*)d_in[1];
    const int*   input_length = (const int*)d_in[2];
    const int*   label_length = (const int*)d_in[3];
    float* out = (float*)d_out;

    ctc_kernel<<<Bc, NW * 64, 0, stream>>>(y_true, y_pred, input_length,
                                           label_length, out);
}